// Round 8
// baseline (91.714 us; speedup 1.0000x reference)
//
#include <hip/hip_runtime.h>

typedef float f32x4 __attribute__((ext_vector_type(4)));
typedef __bf16 bf16x8 __attribute__((ext_vector_type(8)));
typedef __bf16 bf16x4 __attribute__((ext_vector_type(4)));

#define T_ 2048
#define DE 1024
#define DQ 64
#define SCALE 0.125f

// ---------- kernel 0: pack W (3x [1024][64] f32) into fragment-major bf16 Wf.
// Wf[(kc*12 + t)*64 + lane][8]: elem j = W[kc*32+(lane>>4)*8+j][(t&3)*16+(lane&15)],
// matrix = t>>2, kc = k/32.  (validated R5-R7)
__global__ __launch_bounds__(256) void kw_pack(
    const float* __restrict__ Wq, const float* __restrict__ Wk,
    const float* __restrict__ Wv, __bf16* __restrict__ Wf)
{
  int tid = blockIdx.x * 256 + threadIdx.x;   // 0..24575 = f*64 + lane
  int lane = tid & 63, f = tid >> 6;
  int t = f % 12, kc = f / 12;
  const float* W = (t < 4) ? Wq : ((t < 8) ? Wk : Wv);
  int nl = (t & 3) * 16 + (lane & 15);
  int k0 = kc * 32 + (lane >> 4) * 8;
  bf16x8 v;
#pragma unroll
  for (int j = 0; j < 8; ++j) v[j] = (__bf16)W[(size_t)(k0 + j) * 64 + nl];
  *(bf16x8*)(Wf + (size_t)tid * 8) = v;
}

// ---------- kernel 1: QKV projection. Block = 32 m-rows, 4 waves = (msub x Khalf).
// Reg-direct streaming (no LDS staging), ZERO barriers in k-loop, 256-VGPR budget
// so the compiler pipelines x loads deep. f32 LDS combine of the two K-halves.
__global__ __launch_bounds__(256, 2) void kproj(
    const float* __restrict__ x, const __bf16* __restrict__ Wf,
    __bf16* __restrict__ Qb, __bf16* __restrict__ Kb, __bf16* __restrict__ Vt)
{
  __shared__ f32x4 parts[2][12][64];          // 24 KB: [msub][nt][lane]
  const int tid = threadIdx.x;
  const int lane = tid & 63;
  const int w = tid >> 6;
  const int col = lane & 15, g = lane >> 4;
  const int msub = w & 1;                     // 16-row half
  const int khalf = w >> 1;                   // K half: kc in [khalf*16, khalf*16+16)
  const int mbase = blockIdx.x * 32;

  f32x4 acc[12];
#pragma unroll
  for (int i = 0; i < 12; ++i) acc[i] = (f32x4){0.f, 0.f, 0.f, 0.f};

  const float* xr = x + (size_t)(mbase + msub * 16 + col) * DE + khalf * 512 + g * 8;
  const __bf16* Wbase = Wf + ((size_t)(khalf * 16 * 12) * 64 + lane) * 8;

#pragma unroll
  for (int ks = 0; ks < 16; ++ks) {
    f32x4 a0 = *(const f32x4*)(xr + ks * 32);
    f32x4 a1 = *(const f32x4*)(xr + ks * 32 + 4);
    bf16x8 af;
#pragma unroll
    for (int j = 0; j < 4; ++j) { af[j] = (__bf16)a0[j]; af[4 + j] = (__bf16)a1[j]; }
    const __bf16* Wp = Wbase + (size_t)ks * 12 * 512;
#pragma unroll
    for (int nt = 0; nt < 12; ++nt) {
      bf16x8 bfr = *(const bf16x8*)(Wp + (size_t)nt * 512);
      acc[nt] = __builtin_amdgcn_mfma_f32_16x16x32_bf16(af, bfr, acc[nt], 0, 0, 0);
    }
  }

  // combine the two K-halves in f32 (one barrier)
  if (khalf == 1) {
#pragma unroll
    for (int nt = 0; nt < 12; ++nt) parts[msub][nt][lane] = acc[nt];
  }
  __syncthreads();
  if (khalf == 0) {
#pragma unroll
    for (int nt = 0; nt < 12; ++nt) acc[nt] += parts[msub][nt][lane];

    // epilogue: D layout row = g*4+r (within 16-row m-sub), col = ti*16 + col
    const int b = mbase >> 11;
    const int mrow = mbase + msub * 16 + g * 4;
    const int trow = (mbase & 2047) + msub * 16 + g * 4;
#pragma unroll
    for (int ti = 0; ti < 12; ++ti) {
      if (ti < 8) {
        __bf16* dst = (ti < 4) ? Qb : Kb;
        int c = (ti & 3) * 16 + col;
#pragma unroll
        for (int r = 0; r < 4; ++r)
          dst[(size_t)(mrow + r) * DQ + c] = (__bf16)acc[ti][r];
      } else {
        int d = (ti - 8) * 16 + col;
        bf16x4 v;
#pragma unroll
        for (int r = 0; r < 4; ++r) v[r] = (__bf16)acc[ti][r];
        *(bf16x4*)(Vt + ((size_t)(b * DQ + d)) * T_ + trow) = v;
      }
    }
  }
}

// ---------- kernel 2: causal flash attention. Block = 32 q-rows, 4 waves split KV
// (KVB=64). 256-VGPR budget + explicit next-iter K prefetch (kfA/kfB rotation).
__global__ __launch_bounds__(256, 2) void kattn(
    const __bf16* __restrict__ Qb, const __bf16* __restrict__ Kb,
    const __bf16* __restrict__ Vt, float* __restrict__ out)
{
  __shared__ float accs[4][32][68];
  __shared__ float mls[4][2][32];
  __shared__ __bf16 plds[4][2][16][72];

  const int tid = threadIdx.x;
  const int lane = tid & 63;
  const int w = tid >> 6;
  const int col = lane & 15, g = lane >> 4;
  const int b = blockIdx.x & 7;
  const int jq = 63 - (blockIdx.x >> 3);
  const int qbase = jq * 32;

  bf16x8 qa[2][2];
#pragma unroll
  for (int mt = 0; mt < 2; ++mt) {
    const __bf16* Qp = Qb + (size_t)(b * T_ + qbase + mt * 16 + col) * DQ + g * 8;
    qa[mt][0] = *(const bf16x8*)(Qp);
    qa[mt][1] = *(const bf16x8*)(Qp + 32);
  }

  const __bf16* Kbb = Kb + (size_t)b * T_ * DQ;
  const __bf16* Vbb = Vt + (size_t)b * DQ * T_;

  f32x4 acc[2][4];
#pragma unroll
  for (int mt = 0; mt < 2; ++mt)
#pragma unroll
    for (int dt = 0; dt < 4; ++dt) acc[mt][dt] = (f32x4){0.f,0.f,0.f,0.f};
  float mrun[2][4], lsum[2][4];
#pragma unroll
  for (int mt = 0; mt < 2; ++mt)
#pragma unroll
    for (int r = 0; r < 4; ++r) { mrun[mt][r] = -1e30f; lsum[mt][r] = 0.f; }

  const int nb = (jq >> 1) + 1;

  // prefetch K for this wave's first iteration (clamped address)
  bf16x8 kfA[4][2];
  {
    const int pb = (w < nb ? w : nb - 1) * 64;
#pragma unroll
    for (int nt = 0; nt < 4; ++nt) {
      const __bf16* Kp = Kbb + (size_t)(pb + nt * 16 + col) * DQ + g * 8;
      kfA[nt][0] = *(const bf16x8*)(Kp);
      kfA[nt][1] = *(const bf16x8*)(Kp + 32);
    }
  }

  for (int it = w; it < nb; it += 4) {
    const int nbase = it * 64;

    // prefetch next iteration's K (clamped; hides K latency under this iter)
    bf16x8 kfB[4][2];
    {
      const int pn = (it + 4 < nb ? it + 4 : nb - 1) * 64;
#pragma unroll
      for (int nt = 0; nt < 4; ++nt) {
        const __bf16* Kp = Kbb + (size_t)(pn + nt * 16 + col) * DQ + g * 8;
        kfB[nt][0] = *(const bf16x8*)(Kp);
        kfB[nt][1] = *(const bf16x8*)(Kp + 32);
      }
    }

    // V fragments (independent of softmax)
    bf16x8 vf[4][2];
#pragma unroll
    for (int dt = 0; dt < 4; ++dt) {
      const __bf16* Vp = Vbb + (size_t)(dt * 16 + col) * T_ + nbase + g * 8;
      vf[dt][0] = *(const bf16x8*)(Vp);
      vf[dt][1] = *(const bf16x8*)(Vp + 32);
    }

    f32x4 s[2][4];
#pragma unroll
    for (int mt = 0; mt < 2; ++mt)
#pragma unroll
      for (int nt = 0; nt < 4; ++nt) {
        f32x4 t = __builtin_amdgcn_mfma_f32_16x16x32_bf16(qa[mt][0], kfA[nt][0],
                                                          (f32x4){0.f,0.f,0.f,0.f}, 0, 0, 0);
        s[mt][nt] = __builtin_amdgcn_mfma_f32_16x16x32_bf16(qa[mt][1], kfA[nt][1], t, 0, 0, 0);
      }

#pragma unroll
    for (int mt = 0; mt < 2; ++mt)
#pragma unroll
      for (int nt = 0; nt < 4; ++nt)
#pragma unroll
        for (int r = 0; r < 4; ++r) s[mt][nt][r] *= SCALE;
    if (it == nb - 1) {
#pragma unroll
      for (int mt = 0; mt < 2; ++mt)
#pragma unroll
        for (int nt = 0; nt < 4; ++nt)
#pragma unroll
          for (int r = 0; r < 4; ++r)
            if (nbase + nt * 16 + col > qbase + mt * 16 + g * 4 + r) s[mt][nt][r] = -1e30f;
    }

    float mv[2][4];
#pragma unroll
    for (int mt = 0; mt < 2; ++mt)
#pragma unroll
      for (int r = 0; r < 4; ++r)
        mv[mt][r] = fmaxf(fmaxf(s[mt][0][r], s[mt][1][r]), fmaxf(s[mt][2][r], s[mt][3][r]));
#pragma unroll
    for (int sh = 1; sh <= 8; sh <<= 1)
#pragma unroll
      for (int mt = 0; mt < 2; ++mt)
#pragma unroll
        for (int r = 0; r < 4; ++r) mv[mt][r] = fmaxf(mv[mt][r], __shfl_xor(mv[mt][r], sh, 64));

#pragma unroll
    for (int mt = 0; mt < 2; ++mt)
#pragma unroll
      for (int r = 0; r < 4; ++r) {
        float mn = fmaxf(mrun[mt][r], mv[mt][r]);
        float rs = __expf(mrun[mt][r] - mn);
        mrun[mt][r] = mn;
        float ps = 0.f;
#pragma unroll
        for (int nt = 0; nt < 4; ++nt) {
          s[mt][nt][r] = __expf(s[mt][nt][r] - mn);
          ps += s[mt][nt][r];
        }
        lsum[mt][r] = lsum[mt][r] * rs + ps;
#pragma unroll
        for (int dt = 0; dt < 4; ++dt) acc[mt][dt][r] *= rs;
      }

#pragma unroll
    for (int mt = 0; mt < 2; ++mt)
#pragma unroll
      for (int nt = 0; nt < 4; ++nt)
#pragma unroll
        for (int r = 0; r < 4; ++r)
          plds[w][mt][g * 4 + r][nt * 16 + col] = (__bf16)s[mt][nt][r];

    bf16x8 pa[2][2];
#pragma unroll
    for (int mt = 0; mt < 2; ++mt) {
      pa[mt][0] = *(const bf16x8*)&plds[w][mt][col][g * 8];
      pa[mt][1] = *(const bf16x8*)&plds[w][mt][col][32 + g * 8];
    }

#pragma unroll
    for (int mt = 0; mt < 2; ++mt)
#pragma unroll
      for (int dt = 0; dt < 4; ++dt) {
        f32x4 t = __builtin_amdgcn_mfma_f32_16x16x32_bf16(pa[mt][0], vf[dt][0], acc[mt][dt], 0, 0, 0);
        acc[mt][dt] = __builtin_amdgcn_mfma_f32_16x16x32_bf16(pa[mt][1], vf[dt][1], t, 0, 0, 0);
      }

#pragma unroll
    for (int nt = 0; nt < 4; ++nt) {
      kfA[nt][0] = kfB[nt][0];
      kfA[nt][1] = kfB[nt][1];
    }
  }

#pragma unroll
  for (int sh = 1; sh <= 8; sh <<= 1)
#pragma unroll
    for (int mt = 0; mt < 2; ++mt)
#pragma unroll
      for (int r = 0; r < 4; ++r) lsum[mt][r] += __shfl_xor(lsum[mt][r], sh, 64);

#pragma unroll
  for (int mt = 0; mt < 2; ++mt)
#pragma unroll
    for (int r = 0; r < 4; ++r) {
      int row = mt * 16 + g * 4 + r;
      accs[w][row][col]      = acc[mt][0][r];
      accs[w][row][col + 16] = acc[mt][1][r];
      accs[w][row][col + 32] = acc[mt][2][r];
      accs[w][row][col + 48] = acc[mt][3][r];
      if (col == 0) { mls[w][0][row] = mrun[mt][r]; mls[w][1][row] = lsum[mt][r]; }
    }
  __syncthreads();

#pragma unroll
  for (int pass = 0; pass < 2; ++pass) {
    int row = pass * 16 + (tid >> 4);
    int c4 = (tid & 15) * 4;
    float m0 = mls[0][0][row], m1 = mls[1][0][row];
    float m2 = mls[2][0][row], m3 = mls[3][0][row];
    float M = fmaxf(fmaxf(m0, m1), fmaxf(m2, m3));
    float s0 = __expf(m0 - M), s1 = __expf(m1 - M);
    float s2 = __expf(m2 - M), s3 = __expf(m3 - M);
    float L = s0 * mls[0][1][row] + s1 * mls[1][1][row]
            + s2 * mls[2][1][row] + s3 * mls[3][1][row];
    f32x4 a0 = *(const f32x4*)&accs[0][row][c4];
    f32x4 a1 = *(const f32x4*)&accs[1][row][c4];
    f32x4 a2 = *(const f32x4*)&accs[2][row][c4];
    f32x4 a3 = *(const f32x4*)&accs[3][row][c4];
    float inv = 1.f / L;
    f32x4 o;
#pragma unroll
    for (int j = 0; j < 4; ++j)
      o[j] = (s0 * a0[j] + s1 * a1[j] + s2 * a2[j] + s3 * a3[j]) * inv;
    *(f32x4*)(out + (size_t)(b * T_ + qbase + row) * DQ + c4) = o;
  }
}

extern "C" void kernel_launch(void* const* d_in, const int* in_sizes, int n_in,
                              void* d_out, int out_size, void* d_ws, size_t ws_size,
                              hipStream_t stream)
{
  const float* x  = (const float*)d_in[0];
  const float* Wq = (const float*)d_in[1];
  const float* Wk = (const float*)d_in[2];
  const float* Wv = (const float*)d_in[3];
  float* out = (float*)d_out;

  char* ws = (char*)d_ws;
  __bf16* Wf = (__bf16*)(ws);                                   // 384 KiB
  __bf16* Qb = (__bf16*)(ws + 0x80000);                         // 2 MiB
  __bf16* Kb = (__bf16*)(ws + 0x80000 + 0x200000);              // 2 MiB
  __bf16* Vt = (__bf16*)(ws + 0x80000 + 0x400000);              // 2 MiB

  kw_pack<<<96, 256, 0, stream>>>(Wq, Wk, Wv, Wf);
  kproj<<<512, 256, 0, stream>>>(x, Wf, Qb, Kb, Vt);
  kattn<<<512, 256, 0, stream>>>(Qb, Kb, Vt, out);
}

// Round 9
// 50.945 us; speedup vs baseline: 1.8003x; 1.8003x over previous
//
#include <hip/hip_runtime.h>

typedef float f32x4 __attribute__((ext_vector_type(4)));
typedef __bf16 bf16x8 __attribute__((ext_vector_type(8)));
typedef __bf16 bf16x4 __attribute__((ext_vector_type(4)));

#define T_ 2048
#define DE 1024
#define DQ 64
#define SCALE 0.125f

#define GL16(gp, lp)                                                        \
  __builtin_amdgcn_global_load_lds(                                         \
      (const __attribute__((address_space(1))) void*)(gp),                  \
      (__attribute__((address_space(3))) void*)(lp), 16, 0, 0)

#define WAITVM(N) asm volatile("s_waitcnt vmcnt(" #N ")" ::: "memory")

// ---------- kernel 0: pack W (3x [1024][64] f32) into fragment-major bf16 Wf.
// Wf[(kc*12 + t)*64 + lane][8]: elem j = W[kc*32+(lane>>4)*8+j][(t&3)*16+(lane&15)],
// matrix = t>>2, kc = k/32.  (validated R5-R8)
__global__ __launch_bounds__(256) void kw_pack(
    const float* __restrict__ Wq, const float* __restrict__ Wk,
    const float* __restrict__ Wv, __bf16* __restrict__ Wf)
{
  int tid = blockIdx.x * 256 + threadIdx.x;   // 0..24575 = f*64 + lane
  int lane = tid & 63, f = tid >> 6;
  int t = f % 12, kc = f / 12;
  const float* W = (t < 4) ? Wq : ((t < 8) ? Wk : Wv);
  int nl = (t & 3) * 16 + (lane & 15);
  int k0 = kc * 32 + (lane >> 4) * 8;
  bf16x8 v;
#pragma unroll
  for (int j = 0; j < 8; ++j) v[j] = (__bf16)W[(size_t)(k0 + j) * 64 + nl];
  *(bf16x8*)(Wf + (size_t)tid * 8) = v;
}

// ---------- kernel 1: QKV projection. Block = 32 m-rows, 4 waves = 2 msub x 2 ngrp.
// Counted-vmcnt pipeline: A (x, HBM) 3 buffers staged 2 ahead; B (Wf, L2) 2 buffers
// staged 1 ahead. Per iter: vmcnt(2) -> s_barrier -> issue next stages -> compute.
// All staging via global_load_lds (compiler can't defeat it).
__global__ __launch_bounds__(256) void kproj(
    const float* __restrict__ x, const __bf16* __restrict__ Wf,
    __bf16* __restrict__ Qb, __bf16* __restrict__ Kb, __bf16* __restrict__ Vt)
{
  __shared__ char lds[3 * 8192 + 2 * 24576];  // A: [0,24K)  B: [24K,72K)
  const int tid = threadIdx.x;
  const int lane = tid & 63;
  const int w = tid >> 6;
  const int col = lane & 15, g = lane >> 4;
  const int msub = w & 1;                     // 16-row half
  const int ng = w >> 1;                      // n-tile group: tiles ng*6 .. ng*6+5
  const int mbase = blockIdx.x * 32;

  // A staging map (R7-validated): chunk q=w*2+cc, row=q*4+(l>>4), slot (l&15);
  // source pre-swizzled by ((row&7)<<4), read side applies same XOR.
  size_t gsrcA[2];
  int ldstA[2];
#pragma unroll
  for (int cc = 0; cc < 2; ++cc) {
    int q = w * 2 + cc;
    int row = q * 4 + (lane >> 4);
    int kbyte = ((lane & 15) * 16) ^ ((row & 7) << 4);
    gsrcA[cc] = (size_t)(mbase + row) * 4096 + (size_t)kbyte;
    ldstA[cc] = q * 1024 + lane * 16;
  }
  // B staging map: linear copy of Wf's contiguous 24KB k-step slab.
  int ofsB[6];
#pragma unroll
  for (int cc = 0; cc < 6; ++cc) ofsB[cc] = (w * 6 + cc) * 1024 + lane * 16;

  f32x4 acc[6];
#pragma unroll
  for (int i = 0; i < 6; ++i) acc[i] = (f32x4){0.f, 0.f, 0.f, 0.f};

  const char* xb = (const char*)x;
  const char* wb = (const char*)Wf;

#define STAGE_A(ks)                                                         \
  {                                                                         \
    char* lb = &lds[((ks) % 3) * 8192];                                     \
    _Pragma("unroll")                                                       \
    for (int cc = 0; cc < 2; ++cc)                                          \
      GL16(xb + gsrcA[cc] + (size_t)(ks) * 256, lb + ldstA[cc]);            \
  }
#define STAGE_B(ks)                                                         \
  {                                                                         \
    char* lb = &lds[24576 + ((ks) & 1) * 24576];                            \
    _Pragma("unroll")                                                       \
    for (int cc = 0; cc < 6; ++cc)                                          \
      GL16(wb + (size_t)(ks) * 24576 + ofsB[cc], lb + ofsB[cc]);            \
  }
#define KSTEP(ks)                                                           \
  {                                                                         \
    const char* la = &lds[((ks) % 3) * 8192];                               \
    const char* lbB = &lds[24576 + ((ks) & 1) * 24576];                     \
    const int arow = msub * 16 + col;                                       \
    const char* abase = la + arow * 256;                                    \
    const int sw = (arow & 7) << 4;                                         \
    _Pragma("unroll")                                                       \
    for (int kh = 0; kh < 2; ++kh) {                                        \
      int kb = kh * 128 + g * 32;                                           \
      f32x4 a0 = *(const f32x4*)(abase + (kb ^ sw));                        \
      f32x4 a1 = *(const f32x4*)(abase + ((kb + 16) ^ sw));                 \
      bf16x8 af;                                                            \
      _Pragma("unroll")                                                     \
      for (int j = 0; j < 4; ++j) { af[j] = (__bf16)a0[j]; af[4 + j] = (__bf16)a1[j]; } \
      _Pragma("unroll")                                                     \
      for (int ii = 0; ii < 6; ++ii) {                                      \
        int nt = ng * 6 + ii;                                               \
        bf16x8 bfr = *(const bf16x8*)(lbB + ((kh * 12 + nt) * 64 + lane) * 16); \
        acc[ii] = __builtin_amdgcn_mfma_f32_16x16x32_bf16(af, bfr, acc[ii], 0, 0, 0); \
      }                                                                     \
    }                                                                       \
  }
// one pipeline iteration; doB/doA are compile-time 0/1
#define ITER(ks, vm, doB, doA)                                              \
  WAITVM(vm);                                                               \
  __builtin_amdgcn_s_barrier();                                             \
  __builtin_amdgcn_sched_barrier(0);                                        \
  if (doB) STAGE_B((ks) + 1);                                               \
  if (doA) STAGE_A((ks) + 2);                                               \
  KSTEP(ks);

  // prologue: A(0), B(0), A(1)  -> iter0's vmcnt(2) retires A(0)+B(0), keeps A(1)
  STAGE_A(0);
  STAGE_B(0);
  STAGE_A(1);

  ITER(0, 2, 1, 1)  ITER(1, 2, 1, 1)  ITER(2, 2, 1, 1)  ITER(3, 2, 1, 1)
  ITER(4, 2, 1, 1)  ITER(5, 2, 1, 1)  ITER(6, 2, 1, 1)  ITER(7, 2, 1, 1)
  ITER(8, 2, 1, 1)  ITER(9, 2, 1, 1)  ITER(10, 2, 1, 1) ITER(11, 2, 1, 1)
  ITER(12, 2, 1, 1) ITER(13, 2, 1, 1) ITER(14, 2, 1, 0) ITER(15, 0, 0, 0)

#undef ITER
#undef KSTEP
#undef STAGE_B
#undef STAGE_A

  // epilogue: D layout row = g*4+r (within 16-row m-sub), col = ti*16 + col
  const int b = mbase >> 11;
  const int mrow = mbase + msub * 16 + g * 4;
  const int trow = (mbase & 2047) + msub * 16 + g * 4;
#pragma unroll
  for (int ii = 0; ii < 6; ++ii) {
    int ti = ng * 6 + ii;
    if (ti < 8) {
      __bf16* dst = (ti < 4) ? Qb : Kb;
      int c = (ti & 3) * 16 + col;
#pragma unroll
      for (int r = 0; r < 4; ++r)
        dst[(size_t)(mrow + r) * DQ + c] = (__bf16)acc[ii][r];
    } else {
      int d = (ti - 8) * 16 + col;
      bf16x4 v;
#pragma unroll
      for (int r = 0; r < 4; ++r) v[r] = (__bf16)acc[ii][r];
      *(bf16x4*)(Vt + ((size_t)(b * DQ + d)) * T_ + trow) = v;
    }
  }
}

// ---------- kernel 2: causal flash attention (R3/R6 version, proven ~23us).
// Block = 32 q-rows, 4 waves split KV (KVB=64), LDS combine.
__global__ __launch_bounds__(256) void kattn(
    const __bf16* __restrict__ Qb, const __bf16* __restrict__ Kb,
    const __bf16* __restrict__ Vt, float* __restrict__ out)
{
  __shared__ float accs[4][32][68];
  __shared__ float mls[4][2][32];
  __shared__ __bf16 plds[4][2][16][72];

  const int tid = threadIdx.x;
  const int lane = tid & 63;
  const int w = tid >> 6;
  const int col = lane & 15, g = lane >> 4;
  const int b = blockIdx.x & 7;
  const int jq = 63 - (blockIdx.x >> 3);
  const int qbase = jq * 32;

  bf16x8 qa[2][2];
#pragma unroll
  for (int mt = 0; mt < 2; ++mt) {
    const __bf16* Qp = Qb + (size_t)(b * T_ + qbase + mt * 16 + col) * DQ + g * 8;
    qa[mt][0] = *(const bf16x8*)(Qp);
    qa[mt][1] = *(const bf16x8*)(Qp + 32);
  }

  const __bf16* Kbb = Kb + (size_t)b * T_ * DQ;
  const __bf16* Vbb = Vt + (size_t)b * DQ * T_;

  f32x4 acc[2][4];
#pragma unroll
  for (int mt = 0; mt < 2; ++mt)
#pragma unroll
    for (int dt = 0; dt < 4; ++dt) acc[mt][dt] = (f32x4){0.f,0.f,0.f,0.f};
  float mrun[2][4], lsum[2][4];
#pragma unroll
  for (int mt = 0; mt < 2; ++mt)
#pragma unroll
    for (int r = 0; r < 4; ++r) { mrun[mt][r] = -1e30f; lsum[mt][r] = 0.f; }

  const int nb = (jq >> 1) + 1;
  for (int it = w; it < nb; it += 4) {
    const int nbase = it * 64;

    bf16x8 kf_[4][2];
#pragma unroll
    for (int nt = 0; nt < 4; ++nt) {
      const __bf16* Kp = Kbb + (size_t)(nbase + nt * 16 + col) * DQ + g * 8;
      kf_[nt][0] = *(const bf16x8*)(Kp);
      kf_[nt][1] = *(const bf16x8*)(Kp + 32);
    }

    f32x4 s[2][4];
#pragma unroll
    for (int mt = 0; mt < 2; ++mt)
#pragma unroll
      for (int nt = 0; nt < 4; ++nt) {
        f32x4 t = __builtin_amdgcn_mfma_f32_16x16x32_bf16(qa[mt][0], kf_[nt][0],
                                                          (f32x4){0.f,0.f,0.f,0.f}, 0, 0, 0);
        s[mt][nt] = __builtin_amdgcn_mfma_f32_16x16x32_bf16(qa[mt][1], kf_[nt][1], t, 0, 0, 0);
      }

    bf16x8 vf[4][2];
#pragma unroll
    for (int dt = 0; dt < 4; ++dt) {
      const __bf16* Vp = Vbb + (size_t)(dt * 16 + col) * T_ + nbase + g * 8;
      vf[dt][0] = *(const bf16x8*)(Vp);
      vf[dt][1] = *(const bf16x8*)(Vp + 32);
    }

#pragma unroll
    for (int mt = 0; mt < 2; ++mt)
#pragma unroll
      for (int nt = 0; nt < 4; ++nt)
#pragma unroll
        for (int r = 0; r < 4; ++r) s[mt][nt][r] *= SCALE;
    if (it == nb - 1) {
#pragma unroll
      for (int mt = 0; mt < 2; ++mt)
#pragma unroll
        for (int nt = 0; nt < 4; ++nt)
#pragma unroll
          for (int r = 0; r < 4; ++r)
            if (nbase + nt * 16 + col > qbase + mt * 16 + g * 4 + r) s[mt][nt][r] = -1e30f;
    }

    float mv[2][4];
#pragma unroll
    for (int mt = 0; mt < 2; ++mt)
#pragma unroll
      for (int r = 0; r < 4; ++r)
        mv[mt][r] = fmaxf(fmaxf(s[mt][0][r], s[mt][1][r]), fmaxf(s[mt][2][r], s[mt][3][r]));
#pragma unroll
    for (int sh = 1; sh <= 8; sh <<= 1)
#pragma unroll
      for (int mt = 0; mt < 2; ++mt)
#pragma unroll
        for (int r = 0; r < 4; ++r) mv[mt][r] = fmaxf(mv[mt][r], __shfl_xor(mv[mt][r], sh, 64));

#pragma unroll
    for (int mt = 0; mt < 2; ++mt)
#pragma unroll
      for (int r = 0; r < 4; ++r) {
        float mn = fmaxf(mrun[mt][r], mv[mt][r]);
        float rs = __expf(mrun[mt][r] - mn);
        mrun[mt][r] = mn;
        float ps = 0.f;
#pragma unroll
        for (int nt = 0; nt < 4; ++nt) {
          s[mt][nt][r] = __expf(s[mt][nt][r] - mn);
          ps += s[mt][nt][r];
        }
        lsum[mt][r] = lsum[mt][r] * rs + ps;
#pragma unroll
        for (int dt = 0; dt < 4; ++dt) acc[mt][dt][r] *= rs;
      }

#pragma unroll
    for (int mt = 0; mt < 2; ++mt)
#pragma unroll
      for (int nt = 0; nt < 4; ++nt)
#pragma unroll
        for (int r = 0; r < 4; ++r)
          plds[w][mt][g * 4 + r][nt * 16 + col] = (__bf16)s[mt][nt][r];

    bf16x8 pa[2][2];
#pragma unroll
    for (int mt = 0; mt < 2; ++mt) {
      pa[mt][0] = *(const bf16x8*)&plds[w][mt][col][g * 8];
      pa[mt][1] = *(const bf16x8*)&plds[w][mt][col][32 + g * 8];
    }

#pragma unroll
    for (int mt = 0; mt < 2; ++mt)
#pragma unroll
      for (int dt = 0; dt < 4; ++dt) {
        f32x4 t = __builtin_amdgcn_mfma_f32_16x16x32_bf16(pa[mt][0], vf[dt][0], acc[mt][dt], 0, 0, 0);
        acc[mt][dt] = __builtin_amdgcn_mfma_f32_16x16x32_bf16(pa[mt][1], vf[dt][1], t, 0, 0, 0);
      }
  }

#pragma unroll
  for (int sh = 1; sh <= 8; sh <<= 1)
#pragma unroll
    for (int mt = 0; mt < 2; ++mt)
#pragma unroll
      for (int r = 0; r < 4; ++r) lsum[mt][r] += __shfl_xor(lsum[mt][r], sh, 64);

#pragma unroll
  for (int mt = 0; mt < 2; ++mt)
#pragma unroll
    for (int r = 0; r < 4; ++r) {
      int row = mt * 16 + g * 4 + r;
      accs[w][row][col]      = acc[mt][0][r];
      accs[w][row][col + 16] = acc[mt][1][r];
      accs[w][row][col + 32] = acc[mt][2][r];
      accs[w][row][col + 48] = acc[mt][3][r];
      if (col == 0) { mls[w][0][row] = mrun[mt][r]; mls[w][1][row] = lsum[mt][r]; }
    }
  __syncthreads();

#pragma unroll
  for (int pass = 0; pass < 2; ++pass) {
    int row = pass * 16 + (tid >> 4);
    int c4 = (tid & 15) * 4;
    float m0 = mls[0][0][row], m1 = mls[1][0][row];
    float m2 = mls[2][0][row], m3 = mls[3][0][row];
    float M = fmaxf(fmaxf(m0, m1), fmaxf(m2, m3));
    float s0 = __expf(m0 - M), s1 = __expf(m1 - M);
    float s2 = __expf(m2 - M), s3 = __expf(m3 - M);
    float L = s0 * mls[0][1][row] + s1 * mls[1][1][row]
            + s2 * mls[2][1][row] + s3 * mls[3][1][row];
    f32x4 a0 = *(const f32x4*)&accs[0][row][c4];
    f32x4 a1 = *(const f32x4*)&accs[1][row][c4];
    f32x4 a2 = *(const f32x4*)&accs[2][row][c4];
    f32x4 a3 = *(const f32x4*)&accs[3][row][c4];
    float inv = 1.f / L;
    f32x4 o;
#pragma unroll
    for (int j = 0; j < 4; ++j)
      o[j] = (s0 * a0[j] + s1 * a1[j] + s2 * a2[j] + s3 * a3[j]) * inv;
    *(f32x4*)(out + (size_t)(b * T_ + qbase + row) * DQ + c4) = o;
  }
}

extern "C" void kernel_launch(void* const* d_in, const int* in_sizes, int n_in,
                              void* d_out, int out_size, void* d_ws, size_t ws_size,
                              hipStream_t stream)
{
  const float* x  = (const float*)d_in[0];
  const float* Wq = (const float*)d_in[1];
  const float* Wk = (const float*)d_in[2];
  const float* Wv = (const float*)d_in[3];
  float* out = (float*)d_out;

  char* ws = (char*)d_ws;
  __bf16* Wf = (__bf16*)(ws);                                   // 384 KiB
  __bf16* Qb = (__bf16*)(ws + 0x80000);                         // 2 MiB
  __bf16* Kb = (__bf16*)(ws + 0x80000 + 0x200000);              // 2 MiB
  __bf16* Vt = (__bf16*)(ws + 0x80000 + 0x400000);              // 2 MiB

  kw_pack<<<96, 256, 0, stream>>>(Wq, Wk, Wv, Wf);
  kproj<<<512, 256, 0, stream>>>(x, Wf, Qb, Kb, Vt);
  kattn<<<512, 256, 0, stream>>>(Qb, Kb, Vt, out);
}